// Round 3
// baseline (1267.571 us; speedup 1.0000x reference)
//
#include <hip/hip_runtime.h>
#include <hip/hip_bf16.h>
#include <stdint.h>

#define LQ 2048
#define DM 1024
#define NH 16
#define HD 64
#define NPAIR 32
#define SCALE_F 0.125f

// swizzled LDS float index: 64-float row stride, 16B chunks XOR'd by row&15.
// column reads at fixed chunk hit a permutation of chunks across rows -> <=2-way (free).
#define SWZ(row, ch) (((row) << 6) + ((((ch) ^ ((row) & 15))) << 2))

// ---------------- Q projections: Qa = rope(x@wq_attn), Qr = x@wq_rel ----------------
#define QROWS 16
__global__ __launch_bounds__(256) void k_proj_q(
    const float* __restrict__ x, const float* __restrict__ wqa, const float* __restrict__ wqr,
    const float* __restrict__ fcos, const float* __restrict__ fsin,
    float* __restrict__ Qa, float* __restrict__ Qr)
{
    __shared__ float xS[QROWS * DM];   // 64 KB
    const int bid = blockIdx.x;
    const int i0 = (bid >> 2) * QROWS;
    const int m = (bid >> 1) & 1;      // 0: attn (rope), 1: rel
    const int half = bid & 1;
    const int tid = threadIdx.x;
    {
        const float4* src = (const float4*)(x + (size_t)i0 * DM);
        float4* dst4 = (float4*)xS;
        for (int t = tid; t < QROWS * DM / 4; t += 256) dst4[t] = src[t];
    }
    __syncthreads();
    const int q = half * 256 + tid;    // global pair index 0..511, cols 2q, 2q+1
    const float2* __restrict__ w2 = (const float2*)(m ? wqr : wqa);  // 512 pairs per row
    float ae[QROWS], ao[QROWS];
#pragma unroll
    for (int r = 0; r < QROWS; ++r) { ae[r] = 0.f; ao[r] = 0.f; }
    for (int k = 0; k < DM; k += 4) {
        float2 w0 = w2[(size_t)(k + 0) * (DM / 2) + q];
        float2 w1 = w2[(size_t)(k + 1) * (DM / 2) + q];
        float2 w2v = w2[(size_t)(k + 2) * (DM / 2) + q];
        float2 w3 = w2[(size_t)(k + 3) * (DM / 2) + q];
#pragma unroll
        for (int r = 0; r < QROWS; ++r) {
            float4 xv = *(const float4*)&xS[r * DM + k];
            ae[r] = fmaf(xv.x, w0.x, ae[r]);  ao[r] = fmaf(xv.x, w0.y, ao[r]);
            ae[r] = fmaf(xv.y, w1.x, ae[r]);  ao[r] = fmaf(xv.y, w1.y, ao[r]);
            ae[r] = fmaf(xv.z, w2v.x, ae[r]); ao[r] = fmaf(xv.z, w2v.y, ao[r]);
            ae[r] = fmaf(xv.w, w3.x, ae[r]);  ao[r] = fmaf(xv.w, w3.y, ao[r]);
        }
    }
    float* __restrict__ dst = m ? Qr : Qa;
    const int p = q & (NPAIR - 1);
#pragma unroll
    for (int r = 0; r < QROWS; ++r) {
        float oe = ae[r], oo = ao[r];
        if (m == 0) {
            float c = fcos[(i0 + r) * NPAIR + p];
            float s = fsin[(i0 + r) * NPAIR + p];
            oe = ae[r] * c - ao[r] * s;
            oo = ae[r] * s + ao[r] * c;
        }
        *(float2*)&dst[(size_t)(i0 + r) * DM + 2 * q] = make_float2(oe, oo);
    }
}

// ---------------- KV projections: Ka = rope(x@wk_attn), Kr = x@wk_rel, SV = symbols@wv ----
#define KVROWS 8
__global__ __launch_bounds__(128) void k_proj_kv(
    const float* __restrict__ x, const float* __restrict__ symbols,
    const float* __restrict__ wka, const float* __restrict__ wkr, const float* __restrict__ wv,
    const float* __restrict__ fcos, const float* __restrict__ fsin,
    float* __restrict__ Ka, float* __restrict__ Kr, float* __restrict__ SV)
{
    __shared__ float xS[KVROWS * DM], sS[KVROWS * DM];   // 32KB + 32KB
    const int i0 = blockIdx.x * KVROWS;
    const int tid = threadIdx.x;
    {
        const float4* sx = (const float4*)(x + (size_t)i0 * DM);
        const float4* ss = (const float4*)(symbols + (size_t)i0 * DM);
        for (int t = tid; t < KVROWS * DM / 4; t += 128) {
            ((float4*)xS)[t] = sx[t];
            ((float4*)sS)[t] = ss[t];
        }
    }
    __syncthreads();
    if (tid >= 96) return;
    const int m = tid >> 5;        // 0: Ka, 1: Kr, 2: SV
    const int p = tid & 31;
    const float2* __restrict__ w2 = (const float2*)(m == 0 ? wka : (m == 1 ? wkr : wv)); // 32 pairs/row
    const float* __restrict__ src = (m == 2) ? sS : xS;
    float ae[KVROWS], ao[KVROWS];
#pragma unroll
    for (int r = 0; r < KVROWS; ++r) { ae[r] = 0.f; ao[r] = 0.f; }
    for (int k = 0; k < DM; ++k) {
        float2 w = w2[k * 32 + p];
#pragma unroll
        for (int r = 0; r < KVROWS; ++r) {
            float xv = src[r * DM + k];
            ae[r] = fmaf(xv, w.x, ae[r]);
            ao[r] = fmaf(xv, w.y, ao[r]);
        }
    }
    float* __restrict__ dst = (m == 0 ? Ka : (m == 1 ? Kr : SV));
#pragma unroll
    for (int r = 0; r < KVROWS; ++r) {
        float oe = ae[r], oo = ao[r];
        if (m == 0) {
            float c = fcos[(i0 + r) * NPAIR + p];
            float s = fsin[(i0 + r) * NPAIR + p];
            oe = ae[r] * c - ao[r] * s;
            oo = ae[r] * s + ao[r] * c;
        }
        dst[(i0 + r) * HD + 2 * p] = oe;
        dst[(i0 + r) * HD + 2 * p + 1] = oo;
    }
}

// ---------------- rel scores: rel[h,i,j] = scale * Qr[i,h,:]·Kr[j,:]  (full, no mask) ----
__global__ __launch_bounds__(256) void k_rel(
    const float* __restrict__ Qr, const float* __restrict__ Kr, float* __restrict__ relout)
{
    __shared__ float QS[128 * 68];   // 34.8 KB
    __shared__ float KS[64 * 68];    // 17.4 KB
    const int j0 = blockIdx.x * 64, i0 = blockIdx.y * 128, h = blockIdx.z;
    const int tid = threadIdx.x;
    for (int t = tid; t < 128 * 16; t += 256) {
        int r = t >> 4, c4 = (t & 15) << 2;
        *(float4*)&QS[r * 68 + c4] = *(const float4*)&Qr[(size_t)(i0 + r) * DM + h * HD + c4];
    }
    for (int t = tid; t < 64 * 16; t += 256) {
        int r = t >> 4, c4 = (t & 15) << 2;
        *(float4*)&KS[r * 68 + c4] = *(const float4*)&Kr[(j0 + r) * HD + c4];
    }
    __syncthreads();
    const int ti = tid & 15, tj = tid >> 4;
    float acc[8][4] = {};
#pragma unroll 2
    for (int d = 0; d < HD; d += 4) {
        float4 kv[4];
#pragma unroll
        for (int b = 0; b < 4; ++b) kv[b] = *(const float4*)&KS[(tj * 4 + b) * 68 + d];
#pragma unroll
        for (int a = 0; a < 8; ++a) {
            float4 qv = *(const float4*)&QS[(ti + 16 * a) * 68 + d];
#pragma unroll
            for (int b = 0; b < 4; ++b) {
                acc[a][b] = fmaf(qv.x, kv[b].x, acc[a][b]);
                acc[a][b] = fmaf(qv.y, kv[b].y, acc[a][b]);
                acc[a][b] = fmaf(qv.z, kv[b].z, acc[a][b]);
                acc[a][b] = fmaf(qv.w, kv[b].w, acc[a][b]);
            }
        }
    }
#pragma unroll
    for (int a = 0; a < 8; ++a) {
        float4 w = make_float4(acc[a][0] * SCALE_F, acc[a][1] * SCALE_F,
                               acc[a][2] * SCALE_F, acc[a][3] * SCALE_F);
        *(float4*)&relout[(size_t)(h * LQ + i0 + ti + 16 * a) * LQ + j0 + tj * 4] = w;
    }
}

// ---------------- fused attention: pipelined single pass + in-kernel renorm tail ------
// Double-buffered K/SV tiles in swizzled (pad-free) LDS: next tile's global loads are
// issued into VGPRs before QK (latency hidden under compute), ds_written into the idle
// buffer during the exp phase. p overlays K[cur] after QK. 3 barriers/tile, no phase
// ever stalls on HBM. 80 KB LDS -> 2 blocks/CU.
__global__ __launch_bounds__(256, 2) void k_attn_fused(
    const float* __restrict__ Qa, const float* __restrict__ Ka, const float* __restrict__ SV,
    const float* __restrict__ relin, float* __restrict__ attnout, float* __restrict__ OutH)
{
    __shared__ float QS[4096];          // Q tile, swizzled; reused as [64][17] L scratch
    __shared__ float Kbuf[2][4096];     // K tiles, swizzled; [cur] reused as p after QK
    __shared__ float SVbuf[2][4096];    // SV tiles, swizzled
    const int bid = blockIdx.x;
    const int h = bid & 15;
    const int m = bid >> 4;                  // 0..31
    const int it = (m < 16) ? m : 47 - m;    // pair sums = 31 across bid,bid+256
    const int i0 = it * 64;
    const int tid = threadIdx.x;
    const int ti = tid & 15, tj = tid >> 4;

    // prologue: stage Q and tile 0 of K/SV (through VGPRs, swizzled ds_write)
#pragma unroll
    for (int c = 0; c < 4; ++c) {
        int t = tid + c * 256;            // chunk id 0..1023
        int r = t >> 4, cc = t & 15;
        *(float4*)&QS[SWZ(r, cc)] =
            *(const float4*)&Qa[(size_t)(i0 + r) * DM + h * HD + (cc << 2)];
        *(float4*)&Kbuf[0][SWZ(r, cc)]  = *(const float4*)&Ka[(size_t)r * HD + (cc << 2)];
        *(float4*)&SVbuf[0][SWZ(r, cc)] = *(const float4*)&SV[(size_t)r * HD + (cc << 2)];
    }
    __syncthreads();

    float l_[4] = {0.f, 0.f, 0.f, 0.f};
    float oacc[4][4] = {};
    for (int jt = 0; jt <= it; ++jt) {
        const int cur = jt & 1;
        const int j0 = jt << 6;
        // prefetch next K/SV tile into VGPRs (drains during QK)
        float4 pk[4], psv[4];
        if (jt < it) {
            const int j0n = j0 + 64;
#pragma unroll
            for (int c = 0; c < 4; ++c) {
                int t = tid + c * 256;
                int r = t >> 4, cc = t & 15;
                pk[c]  = *(const float4*)&Ka[(size_t)(j0n + r) * HD + (cc << 2)];
                psv[c] = *(const float4*)&SV[(size_t)(j0n + r) * HD + (cc << 2)];
            }
        }
        // rel prefetch (consumed in exp phase; overlaps QK)
        const int jb = j0 + tj * 4;
        float4 rv[4];
#pragma unroll
        for (int a = 0; a < 4; ++a)
            rv[a] = *(const float4*)&relin[(size_t)(h * LQ + i0 + ti + 16 * a) * LQ + jb];
        // QK^T on current tile
        const float* Kc = Kbuf[cur];
        float s[4][4] = {};
#pragma unroll 2
        for (int d = 0; d < HD; d += 4) {
            const int dc = d >> 2;
            float4 kv[4];
#pragma unroll
            for (int b = 0; b < 4; ++b) kv[b] = *(const float4*)&Kc[SWZ(tj * 4 + b, dc)];
#pragma unroll
            for (int a = 0; a < 4; ++a) {
                float4 qv = *(const float4*)&QS[SWZ(ti + 16 * a, dc)];
#pragma unroll
                for (int b = 0; b < 4; ++b) {
                    s[a][b] = fmaf(qv.x, kv[b].x, s[a][b]);
                    s[a][b] = fmaf(qv.y, kv[b].y, s[a][b]);
                    s[a][b] = fmaf(qv.z, kv[b].z, s[a][b]);
                    s[a][b] = fmaf(qv.w, kv[b].w, s[a][b]);
                }
            }
        }
        __syncthreads();   // QK reads of Kbuf[cur] done; prefetch regs landed
        // write next tile into idle buffers (read-safe: last touched by PV(jt-1))
        if (jt < it) {
            float* Kn = Kbuf[cur ^ 1];
            float* Sn = SVbuf[cur ^ 1];
#pragma unroll
            for (int c = 0; c < 4; ++c) {
                int t = tid + c * 256;
                int r = t >> 4, cc = t & 15;
                *(float4*)&Kn[SWZ(r, cc)] = pk[c];
                *(float4*)&Sn[SWZ(r, cc)] = psv[c];
            }
        }
        // exp, p = e*rel into Kbuf[cur], unnormalized attn write
        float* Pc = Kbuf[cur];
#pragma unroll
        for (int a = 0; a < 4; ++a) {
            const int i = i0 + ti + 16 * a;
            const float* rl = (const float*)&rv[a];
            float e0 = (jb + 0 <= i) ? __expf(s[a][0] * SCALE_F) : 0.f;
            float e1 = (jb + 1 <= i) ? __expf(s[a][1] * SCALE_F) : 0.f;
            float e2 = (jb + 2 <= i) ? __expf(s[a][2] * SCALE_F) : 0.f;
            float e3 = (jb + 3 <= i) ? __expf(s[a][3] * SCALE_F) : 0.f;
            l_[a] += e0 + e1 + e2 + e3;
            *(float4*)&Pc[SWZ(ti + 16 * a, tj)] =
                make_float4(e0 * rl[0], e1 * rl[1], e2 * rl[2], e3 * rl[3]);
            *(float4*)&attnout[(size_t)(h * LQ + i) * LQ + jb] =
                make_float4(e0, e1, e2, e3);
        }
        __syncthreads();   // p complete
        // PV
        const float* SVc = SVbuf[cur];
#pragma unroll 2
        for (int g = 0; g < 64; g += 4) {
            float4 sv0 = *(const float4*)&SVc[SWZ(g + 0, tj)];
            float4 sv1 = *(const float4*)&SVc[SWZ(g + 1, tj)];
            float4 sv2 = *(const float4*)&SVc[SWZ(g + 2, tj)];
            float4 sv3 = *(const float4*)&SVc[SWZ(g + 3, tj)];
#pragma unroll
            for (int a = 0; a < 4; ++a) {
                float4 p4 = *(const float4*)&Pc[SWZ(ti + 16 * a, g >> 2)];
                oacc[a][0] = fmaf(p4.x, sv0.x, oacc[a][0]);
                oacc[a][1] = fmaf(p4.x, sv0.y, oacc[a][1]);
                oacc[a][2] = fmaf(p4.x, sv0.z, oacc[a][2]);
                oacc[a][3] = fmaf(p4.x, sv0.w, oacc[a][3]);
                oacc[a][0] = fmaf(p4.y, sv1.x, oacc[a][0]);
                oacc[a][1] = fmaf(p4.y, sv1.y, oacc[a][1]);
                oacc[a][2] = fmaf(p4.y, sv1.z, oacc[a][2]);
                oacc[a][3] = fmaf(p4.y, sv1.w, oacc[a][3]);
                oacc[a][0] = fmaf(p4.z, sv2.x, oacc[a][0]);
                oacc[a][1] = fmaf(p4.z, sv2.y, oacc[a][1]);
                oacc[a][2] = fmaf(p4.z, sv2.z, oacc[a][2]);
                oacc[a][3] = fmaf(p4.z, sv2.w, oacc[a][3]);
                oacc[a][0] = fmaf(p4.w, sv3.x, oacc[a][0]);
                oacc[a][1] = fmaf(p4.w, sv3.y, oacc[a][1]);
                oacc[a][2] = fmaf(p4.w, sv3.z, oacc[a][2]);
                oacc[a][3] = fmaf(p4.w, sv3.w, oacc[a][3]);
            }
        }
        __syncthreads();   // PV reads done; buffers recyclable next iteration
    }
    // ---- epilogue: reduce L (QS as scratch), write normalized OutH ----
    float* red = QS;   // [64][17]
#pragma unroll
    for (int a = 0; a < 4; ++a) red[(ti + 16 * a) * 17 + tj] = l_[a];
    __syncthreads();
    if (tid < 64) {
        float Ls = 0.f;
#pragma unroll
        for (int t = 0; t < 16; ++t) Ls += red[tid * 17 + t];
        red[tid * 17 + 16] = 1.0f / Ls;
    }
    __syncthreads();
#pragma unroll
    for (int a = 0; a < 4; ++a) {
        float inv = red[(ti + 16 * a) * 17 + 16];
        *(float4*)&OutH[(size_t)(i0 + ti + 16 * a) * DM + h * HD + tj * 4] =
            make_float4(oacc[a][0] * inv, oacc[a][1] * inv,
                        oacc[a][2] * inv, oacc[a][3] * inv);
    }
    // ---- renorm tail: scale lower region (cache-warm), zero-fill upper ----
    const int lastc4 = (it + 1) * 16;   // f4 groups containing data
    for (int idx = tid; idx < 64 * (LQ / 4); idx += 256) {
        const int r = idx >> 9, c4 = idx & 511;
        float* p = &attnout[(size_t)(h * LQ + i0 + r) * LQ + (c4 << 2)];
        if (c4 < lastc4) {
            const float inv = red[r * 17 + 16];
            float4 v = *(const float4*)p;
            v.x *= inv; v.y *= inv; v.z *= inv; v.w *= inv;
            *(float4*)p = v;
        } else {
            *(float4*)p = make_float4(0.f, 0.f, 0.f, 0.f);
        }
    }
}

// ---------------- final projection: out = OutH @ wo ----------------
__global__ __launch_bounds__(256) void k_outproj(
    const float* __restrict__ OutH, const float* __restrict__ wo, float* __restrict__ outp)
{
    __shared__ float AS[64 * 68];
    __shared__ float BS[64 * 68];
    const int n0 = blockIdx.x * 64, i0 = blockIdx.y * 64;
    const int tid = threadIdx.x;
    const int ti = tid & 15, tj = tid >> 4;
    float acc[4][4] = {};
    for (int kt = 0; kt < DM / 64; ++kt) {
        const int k0 = kt * 64;
        __syncthreads();
        for (int t = tid; t < 64 * 16; t += 256) {
            int r = t >> 4, c4 = (t & 15) << 2;
            *(float4*)&AS[r * 68 + c4] = *(const float4*)&OutH[(size_t)(i0 + r) * DM + k0 + c4];
            *(float4*)&BS[r * 68 + c4] = *(const float4*)&wo[(size_t)(k0 + r) * DM + n0 + c4];
        }
        __syncthreads();
#pragma unroll 2
        for (int kk = 0; kk < 64; kk += 4) {
            float4 b0 = *(const float4*)&BS[(kk + 0) * 68 + tj * 4];
            float4 b1 = *(const float4*)&BS[(kk + 1) * 68 + tj * 4];
            float4 b2 = *(const float4*)&BS[(kk + 2) * 68 + tj * 4];
            float4 b3 = *(const float4*)&BS[(kk + 3) * 68 + tj * 4];
#pragma unroll
            for (int a = 0; a < 4; ++a) {
                float4 av = *(const float4*)&AS[(ti + 16 * a) * 68 + kk];
                acc[a][0] = fmaf(av.x, b0.x, acc[a][0]); acc[a][1] = fmaf(av.x, b0.y, acc[a][1]);
                acc[a][2] = fmaf(av.x, b0.z, acc[a][2]); acc[a][3] = fmaf(av.x, b0.w, acc[a][3]);
                acc[a][0] = fmaf(av.y, b1.x, acc[a][0]); acc[a][1] = fmaf(av.y, b1.y, acc[a][1]);
                acc[a][2] = fmaf(av.y, b1.z, acc[a][2]); acc[a][3] = fmaf(av.y, b1.w, acc[a][3]);
                acc[a][0] = fmaf(av.z, b2.x, acc[a][0]); acc[a][1] = fmaf(av.z, b2.y, acc[a][1]);
                acc[a][2] = fmaf(av.z, b2.z, acc[a][2]); acc[a][3] = fmaf(av.z, b2.w, acc[a][3]);
                acc[a][0] = fmaf(av.w, b3.x, acc[a][0]); acc[a][1] = fmaf(av.w, b3.y, acc[a][1]);
                acc[a][2] = fmaf(av.w, b3.z, acc[a][2]); acc[a][3] = fmaf(av.w, b3.w, acc[a][3]);
            }
        }
    }
#pragma unroll
    for (int a = 0; a < 4; ++a) {
        *(float4*)&outp[(size_t)(i0 + ti + 16 * a) * DM + n0 + tj * 4] =
            make_float4(acc[a][0], acc[a][1], acc[a][2], acc[a][3]);
    }
}

extern "C" void kernel_launch(void* const* d_in, const int* in_sizes, int n_in,
                              void* d_out, int out_size, void* d_ws, size_t ws_size,
                              hipStream_t stream)
{
    const float* x       = (const float*)d_in[0];
    const float* symbols = (const float*)d_in[1];
    const float* fcos    = (const float*)d_in[2];
    const float* fsin    = (const float*)d_in[3];
    const float* wqa     = (const float*)d_in[4];
    const float* wka     = (const float*)d_in[5];
    const float* wqr     = (const float*)d_in[6];
    const float* wkr     = (const float*)d_in[7];
    const float* wv      = (const float*)d_in[8];
    const float* wo      = (const float*)d_in[9];

    float* out_main = (float*)d_out;                     // (2048, 1024) f32
    float* out_attn = out_main + (size_t)LQ * DM;        // (16, 2048, 2048) f32
    float* out_rel  = out_attn + (size_t)NH * LQ * LQ;   // (16, 2048, 2048) f32

    float* ws   = (float*)d_ws;
    float* Qa   = ws;                       // 2048*1024
    float* Qr   = Qa + (size_t)LQ * DM;     // 2048*1024
    float* Ka   = Qr + (size_t)LQ * DM;     // 2048*64
    float* Kr   = Ka + (size_t)LQ * HD;
    float* SV   = Kr + (size_t)LQ * HD;
    float* Mrow = SV + (size_t)LQ * HD;     // (unused, layout kept)
    float* Lrow = Mrow + (size_t)NH * LQ;   // (unused, layout kept)
    float* OutH = Lrow + (size_t)NH * LQ;   // 2048*1024

    k_proj_q<<<dim3((LQ / QROWS) * 4), 256, 0, stream>>>(x, wqa, wqr, fcos, fsin, Qa, Qr);
    k_proj_kv<<<dim3(LQ / KVROWS), 128, 0, stream>>>(x, symbols, wka, wkr, wv, fcos, fsin, Ka, Kr, SV);
    k_rel<<<dim3(32, 16, 16), 256, 0, stream>>>(Qr, Kr, out_rel);
    k_attn_fused<<<dim3(32 * 16), 256, 0, stream>>>(Qa, Ka, SV, out_rel, out_attn, OutH);
    k_outproj<<<dim3(16, 32), 256, 0, stream>>>(OutH, wo, out_main);
}